// Round 6
// baseline (127.555 us; speedup 1.0000x reference)
//
#include <hip/hip_runtime.h>

// Fused 79x69 box-filter mean + (x - mean)/5, SAME zero padding.
// 32x128 output tile per 512-thread block. Vertical 79-tap colsums built by
// TWO threads per halo column (split serial chain), horizontal 69-tap window
// via float4 chunked prefix arithmetic from LDS.

#define HH   512
#define WW   512
#define NIMG 32
#define RH   39            // (79-1)/2
#define RW   34            // (69-1)/2
#define TH   32
#define TW   128
#define HALOC (TW + 2*RW)  // 196 colsum columns per tile
#define LDSC  204          // row stride; 204 % 32 == 12 -> good b128 bank spread
#define SPAN  (TH + 2*RH)  // 110 rows: t = 0..109

__device__ __forceinline__ float hsum4(float4 v) { return (v.x + v.y) + (v.z + v.w); }

template<bool INT>
__device__ __forceinline__ float colload(const float* colp, bool colv, int g) {
    if (INT) {
        return colv ? colp[(size_t)g * WW] : 0.0f;
    } else {
        return (colv && g >= 0 && g < HH) ? colp[(size_t)g * WW] : 0.0f;
    }
}

// Phase 1 for one tile: build cs[k][c] = sum_{t=k}^{k+78} x[gbase+t][c].
// half1 (t=55..109): silent 55..77, then write cs[t-78] = sum(55..t).
// half0 (t=0..54):  silent 32..54, barrier, then cs[t] += sum(t..54), t=31..0.
template<bool INT>
__device__ __forceinline__ void phase1_all(float (*cs)[LDSC], const float* colp,
                                           bool colv, bool active, int gbase,
                                           int half, int c) {
    float S = 0.0f;
    if (half == 1) {
        float a0 = 0, a1 = 0, a2 = 0, a3 = 0;
        #pragma unroll
        for (int t = 55; t < 75; t += 4) {
            a0 += colload<INT>(colp, colv, gbase + t + 0);
            a1 += colload<INT>(colp, colv, gbase + t + 1);
            a2 += colload<INT>(colp, colv, gbase + t + 2);
            a3 += colload<INT>(colp, colv, gbase + t + 3);
        }
        a0 += colload<INT>(colp, colv, gbase + 75);
        a1 += colload<INT>(colp, colv, gbase + 76);
        a2 += colload<INT>(colp, colv, gbase + 77);
        float B = (a0 + a1) + (a2 + a3);
        #pragma unroll
        for (int t = 78; t < 110; ++t) {
            B += colload<INT>(colp, colv, gbase + t);
            if (active) cs[t - 78][c] = B;
        }
    } else {
        float a0 = 0, a1 = 0, a2 = 0, a3 = 0;
        #pragma unroll
        for (int t = 32; t < 52; t += 4) {
            a0 += colload<INT>(colp, colv, gbase + t + 0);
            a1 += colload<INT>(colp, colv, gbase + t + 1);
            a2 += colload<INT>(colp, colv, gbase + t + 2);
            a3 += colload<INT>(colp, colv, gbase + t + 3);
        }
        a0 += colload<INT>(colp, colv, gbase + 52);
        a1 += colload<INT>(colp, colv, gbase + 53);
        a2 += colload<INT>(colp, colv, gbase + 54);
        S = (a0 + a1) + (a2 + a3);
    }
    __syncthreads();                     // half1's cs writes visible
    if (half == 0) {
        #pragma unroll
        for (int t = 31; t >= 0; --t) {
            S += colload<INT>(colp, colv, gbase + t);
            if (active) cs[t][c] += S;
        }
    }
}

__global__ __launch_bounds__(512, 8) void fused_kernel(const float* __restrict__ x,
                                                       float* __restrict__ out) {
    __shared__ float cs[TH][LDSC];

    int b   = blockIdx.x;
    int n   = b >> 6;            // 64 tiles per image (16 x 4)
    int rem = b & 63;
    int h0  = (rem >> 2) * TH;
    int w0  = (rem & 3) * TW;
    int tid = threadIdx.x;

    const float* img = x + (size_t)n * HH * WW;

    // ---------------- Phase 1: vertical colsums, 2 threads per column ------
    int  half   = tid >> 8;       // waves 0-3 -> half0, waves 4-7 -> half1
    int  c      = tid & 255;
    bool active = (c < HALOC);
    int  gw     = w0 - RW + c;
    bool colv   = active && (gw >= 0) && (gw < WW);
    int  gbase  = h0 - RH;
    const float* colp = img + gw;

    if (gbase >= 0 && gbase + SPAN <= HH) {
        phase1_all<true >(cs, colp, colv, active, gbase, half, c);
    } else {
        phase1_all<false>(cs, colp, colv, active, gbase, half, c);
    }
    __syncthreads();

    // ---------------- Phase 2: horizontal 69-tap window + finalize ---------
    const float INV = 1.0f / (79.0f * 69.0f);
    int row = tid >> 4;          // 0..31
    int seg = tid & 15;          // 0..15, 8 outputs each
    int c0  = seg * 8;

    const float4* cp  = (const float4*)(&cs[row][0] + c0);   // 16B-aligned
    const float4* xp4 = (const float4*)(img + (size_t)(h0 + row) * WW + (w0 + c0));
    float4*       op4 = (float4*)(out + (size_t)n * HH * WW
                                      + (size_t)(h0 + row) * WW + (w0 + c0));

    // x loads issued early: latency hides under the LDS prologue
    float4 xi0 = xp4[0], xi1 = xp4[1];

    // T = sum of colsum cols [c0, c0+67]  (17 aligned float4 chunks)
    float4 t4 = make_float4(0, 0, 0, 0), u4 = make_float4(0, 0, 0, 0);
    #pragma unroll
    for (int i = 0; i < 16; i += 2) {
        float4 a = cp[i], bq = cp[i + 1];
        t4.x += a.x;  t4.y += a.y;  t4.z += a.z;  t4.w += a.w;
        u4.x += bq.x; u4.y += bq.y; u4.z += bq.z; u4.w += bq.w;
    }
    float T = hsum4(t4) + hsum4(u4) + hsum4(cp[16]);

    float4 xin[2] = { xi0, xi1 };
    #pragma unroll
    for (int g = 0; g < 2; ++g) {
        float4 vin  = cp[17 + g];   // incoming cols c0+68+4g ..
        float4 vout = cp[g];        // outgoing cols c0+4g ..
        float pin0 = vin.x;
        float pin1 = pin0 + vin.y;
        float pin2 = pin1 + vin.z;
        float pin3 = pin2 + vin.w;
        float po0 = vout.x;
        float po1 = po0 + vout.y;
        float po2 = po1 + vout.z;
        float po3 = po2 + vout.w;

        float4 xi = xin[g];
        float4 o;
        o.x = (xi.x - (T + pin0)       * INV) * 0.2f;
        o.y = (xi.y - (T + pin1 - po0) * INV) * 0.2f;
        o.z = (xi.z - (T + pin2 - po1) * INV) * 0.2f;
        o.w = (xi.w - (T + pin3 - po2) * INV) * 0.2f;
        op4[g] = o;

        T += pin3 - po3;            // slide window by 4
    }
}

extern "C" void kernel_launch(void* const* d_in, const int* in_sizes, int n_in,
                              void* d_out, int out_size, void* d_ws, size_t ws_size,
                              hipStream_t stream) {
    const float* x   = (const float*)d_in[0];
    float*       out = (float*)d_out;

    int nblocks = NIMG * (HH / TH) * (WW / TW);   // 32 * 16 * 4 = 2048
    fused_kernel<<<nblocks, 512, 0, stream>>>(x, out);
}

// Round 7
// 107.288 us; speedup vs baseline: 1.1889x; 1.1889x over previous
//
#include <hip/hip_runtime.h>

// Fused 79x69 box-filter mean + (x - mean)/5, SAME zero padding.
// Full-width tile: 32 rows x 512 cols per 1024-thread block (512 blocks,
// 2 blocks/CU, 32 waves/CU). Phase 1: vertical 79-tap colsums into LDS,
// serial chain split 4 ways (2 cols/thread, conflict-free scalar LDS writes).
// Phase 2: horizontal 69-tap window via aligned float4 prefix arithmetic.

#define HH   512
#define WW   512
#define NIMG 32
#define RH   39            // (79-1)/2
#define RW   34            // (69-1)/2
#define TH   32            // rows per block (full 512-col width)
#define SPAN (TH + 2*RH)   // 110 halo rows, span-local t = 0..109
#define LDSW 584           // 34 zeros | 512 data | 38 zeros (16B-aligned rows)
#define NT   1024

__device__ __forceinline__ float hsum4(float4 v) { return (v.x + v.y) + (v.z + v.w); }

template<bool INT>
__device__ __forceinline__ float ldv(const float* col, int g) {
    if (INT) return col[(size_t)g * WW];
    return (g >= 0 && g < HH) ? col[(size_t)g * WW] : 0.0f;
}

// sum rows [gbase+T0, gbase+T0+N) of two columns (4 independent accumulators)
template<bool INT, int T0, int N>
__device__ __forceinline__ void silent2(const float* cA, const float* cB, int gbase,
                                        float& SA, float& SB) {
    float a0 = 0, a1 = 0, b0 = 0, b1 = 0;
    #pragma unroll
    for (int i = 0; i + 2 <= N; i += 2) {
        a0 += ldv<INT>(cA, gbase + T0 + i);
        b0 += ldv<INT>(cB, gbase + T0 + i);
        a1 += ldv<INT>(cA, gbase + T0 + i + 1);
        b1 += ldv<INT>(cB, gbase + T0 + i + 1);
    }
    if (N & 1) {
        a0 += ldv<INT>(cA, gbase + T0 + N - 1);
        b0 += ldv<INT>(cB, gbase + T0 + N - 1);
    }
    SA = a0 + a1; SB = b0 + b1;
}

// ascending walk t=T0..T0+N-1: S += v[t]; cs[t-78] = S   (U[k] = sum 55..k+78)
template<bool INT, int T0, int N>
__device__ __forceinline__ void walk_up_write(float (*cs)[LDSW], const float* cA,
                                              const float* cB, int gbase,
                                              int lA, int lB, float SA, float SB) {
    #pragma unroll
    for (int t = T0; t < T0 + N; ++t) {
        SA += ldv<INT>(cA, gbase + t);
        SB += ldv<INT>(cB, gbase + t);
        cs[t - 78][lA] = SA;
        cs[t - 78][lB] = SB;
    }
}

// descending walk t=T1..T1-N+1: S += v[t]; cs[t] += S    (L[k] = sum k..54)
template<bool INT, int T1, int N>
__device__ __forceinline__ void walk_dn_add(float (*cs)[LDSW], const float* cA,
                                            const float* cB, int gbase,
                                            int lA, int lB, float SA, float SB) {
    #pragma unroll
    for (int t = T1; t > T1 - N; --t) {
        SA += ldv<INT>(cA, gbase + t);
        SB += ldv<INT>(cB, gbase + t);
        cs[t][lA] += SA;
        cs[t][lB] += SB;
    }
}

// colsum[k] = sum_{t=k}^{k+78} v[t]  (t span-local, rows gbase+t), built as
// U[k] (rows 55..k+78, by q2/q3) then += L[k] (rows k..54, by q0/q1).
template<bool INT>
__device__ __forceinline__ void phase1(float (*cs)[LDSW], const float* img,
                                       int gbase, int tid) {
    int q  = tid >> 8;          // wave-uniform quarter
    int cg = tid & 255;
    const float* cA = img + cg;
    const float* cB = img + cg + 256;
    int lA = 34 + cg, lB = 34 + cg + 256;

    float SA, SB;
    if (q == 0)      silent2<INT, 16, 39>(cA, cB, gbase, SA, SB);
    else if (q == 1) silent2<INT, 32, 23>(cA, cB, gbase, SA, SB);
    else if (q == 2) silent2<INT, 55, 23>(cA, cB, gbase, SA, SB);
    else             silent2<INT, 55, 39>(cA, cB, gbase, SA, SB);

    // zero side pads: LDS cols 0..33 (img -34..-1) and 546..583 (img 512+)
    for (int i = tid; i < TH * 72; i += NT) {
        int r = i / 72, c = i - r * 72;
        cs[r][c < 34 ? c : 512 + c] = 0.0f;
    }

    if (q == 2)      walk_up_write<INT, 78, 16>(cs, cA, cB, gbase, lA, lB, SA, SB);
    else if (q == 3) walk_up_write<INT, 94, 16>(cs, cA, cB, gbase, lA, lB, SA, SB);
    __syncthreads();
    if (q == 0)      walk_dn_add<INT, 15, 16>(cs, cA, cB, gbase, lA, lB, SA, SB);
    else if (q == 1) walk_dn_add<INT, 31, 16>(cs, cA, cB, gbase, lA, lB, SA, SB);
    __syncthreads();
}

__global__ __launch_bounds__(NT, 8) void fused_kernel(const float* __restrict__ x,
                                                      float* __restrict__ out) {
    __shared__ float cs[TH][LDSW];   // 74.75 KB -> 2 blocks/CU

    int d   = blockIdx.x;
    int lin = (d & 7) * 64 + (d >> 3);   // XCD x owns images 4x..4x+3 (all tiles)
    int n   = lin >> 4;
    int h0  = (lin & 15) * TH;
    int tid = threadIdx.x;

    const float* img = x + (size_t)n * HH * WW;
    int gbase = h0 - RH;

    if (gbase >= 0 && gbase + SPAN <= HH) phase1<true >(cs, img, gbase, tid);
    else                                  phase1<false>(cs, img, gbase, tid);

    // ---------------- Phase 2: horizontal 69-tap window + finalize ---------
    const float INV = 1.0f / (79.0f * 69.0f);
    int row = tid >> 5;                 // 0..31
    int c0  = (tid & 31) * 16;          // 16 outputs per thread

    const float4* cp = (const float4*)(&cs[row][0] + c0);  // LDS col c0 = window-left
    const float4* xp = (const float4*)(img + (size_t)(h0 + row) * WW + c0);
    float4*       op = (float4*)(out + (size_t)n * HH * WW
                                     + (size_t)(h0 + row) * WW + c0);

    float4 xin0 = xp[0], xin1 = xp[1], xin2 = xp[2], xin3 = xp[3];

    // T = sum of window cols [c0-34, c0+33] (17 aligned chunks)
    float4 t4 = make_float4(0, 0, 0, 0), u4 = make_float4(0, 0, 0, 0);
    #pragma unroll
    for (int i = 0; i < 16; i += 2) {
        float4 a = cp[i], b = cp[i + 1];
        t4.x += a.x; t4.y += a.y; t4.z += a.z; t4.w += a.w;
        u4.x += b.x; u4.y += b.y; u4.z += b.z; u4.w += b.w;
    }
    float T = hsum4(t4) + hsum4(u4) + hsum4(cp[16]);

    float4 xin[4] = { xin0, xin1, xin2, xin3 };
    #pragma unroll
    for (int g = 0; g < 4; ++g) {
        float4 vin  = cp[17 + g];       // entering cols
        float4 vout = cp[g];            // leaving cols
        float pin0 = vin.x,  pin1 = pin0 + vin.y,
              pin2 = pin1 + vin.z, pin3 = pin2 + vin.w;
        float po0  = vout.x, po1 = po0 + vout.y,
              po2  = po1 + vout.z, po3 = po2 + vout.w;

        float4 xi = xin[g];
        float4 o;
        o.x = (xi.x - (T + pin0)       * INV) * 0.2f;
        o.y = (xi.y - (T + pin1 - po0) * INV) * 0.2f;
        o.z = (xi.z - (T + pin2 - po1) * INV) * 0.2f;
        o.w = (xi.w - (T + pin3 - po2) * INV) * 0.2f;
        op[g] = o;

        T += pin3 - po3;                // slide window by 4
    }
}

extern "C" void kernel_launch(void* const* d_in, const int* in_sizes, int n_in,
                              void* d_out, int out_size, void* d_ws, size_t ws_size,
                              hipStream_t stream) {
    const float* x   = (const float*)d_in[0];
    float*       out = (float*)d_out;

    int nblocks = NIMG * (HH / TH);     // 512 = 2 blocks/CU exactly
    fused_kernel<<<nblocks, NT, 0, stream>>>(x, out);
}

// Round 8
// 95.496 us; speedup vs baseline: 1.3357x; 1.1235x over previous
//
#include <hip/hip_runtime.h>

// Fused 79x69 box-filter mean + (x - mean)/5, SAME zero padding.
// 32-row x full-width (512) band per 512-thread block, 512 blocks (2/CU).
// Phase 1: one thread per column. Preload lo rows (t=0..31) and hi rows
// (t=78..109) into registers as one independent load burst; two 23-row
// 4-acc partial sums (M: t=32..54, U: t=55..77). Sliding walks are pure
// register arithmetic; exactly one LDS write per colsum element, exactly
// 110 row-reads per block (zero duplication).
// Phase 2: horizontal 69-tap window via aligned float4 prefix arithmetic.

#define HH   512
#define WW   512
#define NIMG 32
#define RH   39            // (79-1)/2
#define RW   34            // (69-1)/2
#define TH   32            // output rows per block
#define SPAN 110           // halo rows, span-local t = 0..109 (row = gbase+t)
#define LDSW 584           // 34 zeros | 512 data | 38 zeros per LDS row
#define NT   512

__device__ __forceinline__ float hsum4(float4 v) { return (v.x + v.y) + (v.z + v.w); }

template<bool INT>
__device__ __forceinline__ float ldv(const float* col, int g) {
    if (INT) return col[(size_t)g * WW];
    return (g >= 0 && g < HH) ? col[(size_t)g * WW] : 0.0f;
}

// colsum[k] = sum_{t=k}^{k+78} v[t], k=0..31, split at t=55:
//   L[k] = sum(t=k..54) = lo-walk,  U[k] = sum(t=55..k+78) = hi-walk.
template<bool INT>
__device__ __forceinline__ void phase1(float (*cs)[LDSW], const float* img,
                                       int gbase, int c) {
    const float* col = img + c;

    float lo[32];
    #pragma unroll
    for (int t = 0; t < 32; ++t) lo[t] = ldv<INT>(col, gbase + t);

    float m0 = 0, m1 = 0, m2 = 0, m3 = 0;
    #pragma unroll
    for (int t = 32; t < 52; t += 4) {
        m0 += ldv<INT>(col, gbase + t + 0);
        m1 += ldv<INT>(col, gbase + t + 1);
        m2 += ldv<INT>(col, gbase + t + 2);
        m3 += ldv<INT>(col, gbase + t + 3);
    }
    m0 += ldv<INT>(col, gbase + 52);
    m1 += ldv<INT>(col, gbase + 53);
    m2 += ldv<INT>(col, gbase + 54);
    float M = (m0 + m1) + (m2 + m3);

    float hi[32];
    #pragma unroll
    for (int t = 0; t < 32; ++t) hi[t] = ldv<INT>(col, gbase + 78 + t);

    float u0 = 0, u1 = 0, u2 = 0, u3 = 0;
    #pragma unroll
    for (int t = 55; t < 75; t += 4) {
        u0 += ldv<INT>(col, gbase + t + 0);
        u1 += ldv<INT>(col, gbase + t + 1);
        u2 += ldv<INT>(col, gbase + t + 2);
        u3 += ldv<INT>(col, gbase + t + 3);
    }
    u0 += ldv<INT>(col, gbase + 75);
    u1 += ldv<INT>(col, gbase + 76);
    u2 += ldv<INT>(col, gbase + 77);
    float U = (u0 + u1) + (u2 + u3);

    // U-walk ascending, in place: hi[k] <- U[k] = sum(55..k+78)
    #pragma unroll
    for (int k = 0; k < 32; ++k) { U += hi[k]; hi[k] = U; }

    // L-walk descending: L = sum(k..54); one LDS write per element
    float L = M;
    #pragma unroll
    for (int k = 31; k >= 0; --k) {
        L += lo[k];
        cs[k][34 + c] = L + hi[k];
    }
}

__global__ __launch_bounds__(NT, 4) void fused_kernel(const float* __restrict__ x,
                                                      float* __restrict__ out) {
    __shared__ float cs[TH][LDSW];   // 74.75 KB -> 2 blocks/CU, 16 waves/CU

    int d   = blockIdx.x;
    int lin = (d & 7) * 64 + (d >> 3);   // XCD k owns images 4k..4k+3 entirely
    int n   = lin >> 4;
    int h0  = (lin & 15) * TH;
    int tid = threadIdx.x;

    const float* img = x + (size_t)n * HH * WW;
    int gbase = h0 - RH;

    // zero side pads: LDS cols 0..33 (img cols -34..-1) and 546..583 (512..549)
    for (int i = tid; i < TH * 72; i += NT) {
        int r = i / 72, cc = i - r * 72;
        cs[r][cc < 34 ? cc : 512 + cc] = 0.0f;
    }

    if (gbase >= 0 && gbase + SPAN <= HH) phase1<true >(cs, img, gbase, tid);
    else                                  phase1<false>(cs, img, gbase, tid);
    __syncthreads();

    // ---------------- Phase 2: horizontal 69-tap window + finalize ---------
    // Output col c window = img cols [c-34, c+34] = LDS cols [c, c+68].
    const float INV = 1.0f / (79.0f * 69.0f);
    int row = tid >> 4;                 // 0..31
    int c0  = (tid & 15) * 32;          // 32 outputs per thread

    const float4* cp = (const float4*)(&cs[row][0] + c0);
    const float4* xp = (const float4*)(img + (size_t)(h0 + row) * WW + c0);
    float4*       op = (float4*)(out + (size_t)n * HH * WW
                                     + (size_t)(h0 + row) * WW + c0);

    float4 xin[8];
    #pragma unroll
    for (int i = 0; i < 8; ++i) xin[i] = xp[i];   // early: hides under LDS work

    // T = window sum for first output minus its entering column:
    // LDS cols [c0, c0+67] = 17 aligned float4 chunks
    float4 t4 = make_float4(0, 0, 0, 0), u4 = make_float4(0, 0, 0, 0);
    #pragma unroll
    for (int i = 0; i < 16; i += 2) {
        float4 a = cp[i], b = cp[i + 1];
        t4.x += a.x; t4.y += a.y; t4.z += a.z; t4.w += a.w;
        u4.x += b.x; u4.y += b.y; u4.z += b.z; u4.w += b.w;
    }
    float T = hsum4(t4) + hsum4(u4) + hsum4(cp[16]);

    #pragma unroll
    for (int g = 0; g < 8; ++g) {
        float4 vin  = cp[17 + g];       // entering LDS cols c0+68+4g..
        float4 vout = cp[g];            // leaving  LDS cols c0+4g..
        float pin0 = vin.x,  pin1 = pin0 + vin.y,
              pin2 = pin1 + vin.z, pin3 = pin2 + vin.w;
        float po0  = vout.x, po1 = po0 + vout.y,
              po2  = po1 + vout.z, po3 = po2 + vout.w;

        float4 xi = xin[g];
        float4 o;
        o.x = (xi.x - (T + pin0)       * INV) * 0.2f;
        o.y = (xi.y - (T + pin1 - po0) * INV) * 0.2f;
        o.z = (xi.z - (T + pin2 - po1) * INV) * 0.2f;
        o.w = (xi.w - (T + pin3 - po2) * INV) * 0.2f;
        op[g] = o;

        T += pin3 - po3;                // slide window by 4
    }
}

extern "C" void kernel_launch(void* const* d_in, const int* in_sizes, int n_in,
                              void* d_out, int out_size, void* d_ws, size_t ws_size,
                              hipStream_t stream) {
    const float* x   = (const float*)d_in[0];
    float*       out = (float*)d_out;

    int nblocks = NIMG * (HH / TH);     // 512 = 2 blocks/CU exactly
    fused_kernel<<<nblocks, NT, 0, stream>>>(x, out);
}

// Round 11
// 94.472 us; speedup vs baseline: 1.3502x; 1.0108x over previous
//
#include <hip/hip_runtime.h>
#include <hip/hip_fp16.h>

// Fused 79x69 box-filter mean + (x - mean)/5, SAME zero padding.
// 64-row x full-width band per 1024-thread block (256 blocks, 1/CU,
// 16 waves/CU). Phase 1: thread = (sub-band, column); each of the two
// 32-row sub-bands is an independent register-walk colsum (lo[32]/hi[32]
// burst loads, pure-register sliding walks, one fp16 LDS write per element).
// Sub-band halo overlap (78 rows) is reused intra-block via L1/L2.
// Phase 2: horizontal 69-tap window via 4-col fp16 chunk prefix arithmetic
// from a gap-skewed LDS layout (bank-conflict-free).

#define HH   512
#define WW   512
#define NIMG 32
#define RH   39            // (79-1)/2
#define RW   34            // (69-1)/2
#define TH   64            // output rows per block
#define NT   1024
#define LDSW 658           // skewed half-index row stride (odd half-pairs)

// column -> skewed LDS half-index: +8-half gap per 64 cols (bank spread)
__device__ __forceinline__ int cmap(int c) { return c + ((c >> 6) << 3); }

template<bool INT>
__device__ __forceinline__ float ldv(const float* col, int g) {
    if (INT) return col[(size_t)g * WW];
    return (g >= 0 && g < HH) ? col[(size_t)g * WW] : 0.0f;
}

// One 32-row sub-band: csrow[k][c] = sum_{t=k}^{t=k+78} x[gbase+t][c], k=0..31.
// Split at t=55: L[k]=sum(k..54) (lo-walk), U[k]=sum(55..k+78) (hi-walk).
template<bool INT>
__device__ __forceinline__ void phase1(__half* csrow, const float* img,
                                       int gbase, int c) {
    const float* col = img + c;

    float lo[32];
    #pragma unroll
    for (int t = 0; t < 32; ++t) lo[t] = ldv<INT>(col, gbase + t);

    float m0 = 0, m1 = 0, m2 = 0, m3 = 0;
    #pragma unroll
    for (int t = 32; t < 52; t += 4) {
        m0 += ldv<INT>(col, gbase + t + 0);
        m1 += ldv<INT>(col, gbase + t + 1);
        m2 += ldv<INT>(col, gbase + t + 2);
        m3 += ldv<INT>(col, gbase + t + 3);
    }
    m0 += ldv<INT>(col, gbase + 52);
    m1 += ldv<INT>(col, gbase + 53);
    m2 += ldv<INT>(col, gbase + 54);
    float M = (m0 + m1) + (m2 + m3);

    float hi[32];
    #pragma unroll
    for (int t = 0; t < 32; ++t) hi[t] = ldv<INT>(col, gbase + 78 + t);

    float u0 = 0, u1 = 0, u2 = 0, u3 = 0;
    #pragma unroll
    for (int t = 55; t < 75; t += 4) {
        u0 += ldv<INT>(col, gbase + t + 0);
        u1 += ldv<INT>(col, gbase + t + 1);
        u2 += ldv<INT>(col, gbase + t + 2);
        u3 += ldv<INT>(col, gbase + t + 3);
    }
    u0 += ldv<INT>(col, gbase + 75);
    u1 += ldv<INT>(col, gbase + 76);
    u2 += ldv<INT>(col, gbase + 77);
    float U = (u0 + u1) + (u2 + u3);

    // U-walk ascending in place: hi[k] <- sum(55..k+78)
    #pragma unroll
    for (int k = 0; k < 32; ++k) { U += hi[k]; hi[k] = U; }

    // L-walk descending; single fp16 LDS write per colsum element
    int ci = cmap(34 + c);
    float L = M;
    #pragma unroll
    for (int k = 31; k >= 0; --k) {
        L += lo[k];
        csrow[(size_t)k * LDSW + ci] = __float2half(L + hi[k]);
    }
}

// load 4 consecutive skewed fp16 colsum cols as float4 (8-B aligned)
__device__ __forceinline__ float4 ld4(const __half* row, int cc) {
    const __half2* p = (const __half2*)(row + cmap(cc));
    float2 a = __half22float2(p[0]);
    float2 b = __half22float2(p[1]);
    return make_float4(a.x, a.y, b.x, b.y);
}

__device__ __forceinline__ float hsum4(float4 v) { return (v.x + v.y) + (v.z + v.w); }

__global__ __launch_bounds__(NT, 4) void fused_kernel(const float* __restrict__ x,
                                                      float* __restrict__ out) {
    __shared__ __half cs[TH * LDSW];   // 82.25 KB

    int d   = blockIdx.x;
    int lin = (d & 7) * 32 + (d >> 3); // XCD k owns images 4k..4k+3 entirely
    int n   = lin >> 3;
    int h0  = (lin & 7) * TH;
    int tid = threadIdx.x;

    const float* img = x + (size_t)n * HH * WW;

    // zero pads: LDS cols 0..33 (img -34..-1) and 546..583 (img 512..549)
    for (int i = tid; i < TH * 72; i += NT) {
        int r  = i / 72, cc = i - r * 72;
        int col = (cc < 34) ? cc : (512 + cc);
        cs[(size_t)r * LDSW + cmap(col)] = __float2half(0.0f);
    }

    // ---------------- Phase 1: two 32-row sub-bands, 1 col/thread ----------
    int sub = tid >> 9;                 // waves 0-7 -> rows 0..31, 8-15 -> 32..63
    int c   = tid & 511;
    int gb  = h0 - RH + 32 * sub;
    __half* csrow = cs + (size_t)(32 * sub) * LDSW;
    if (gb >= 0 && gb + 110 <= HH) phase1<true >(csrow, img, gb, c);
    else                           phase1<false>(csrow, img, gb, c);
    __syncthreads();

    // ---------------- Phase 2: horizontal 69-tap window + finalize ---------
    // Output col c window = img cols [c-34, c+34] = LDS cols [c, c+68].
    const float INV = 1.0f / (79.0f * 69.0f);
    int row = tid >> 4;                 // 0..63
    int c0  = (tid & 15) * 32;          // 32 outputs per thread

    const __half*  crow = cs + (size_t)row * LDSW;
    const float4*  xp = (const float4*)(img + (size_t)(h0 + row) * WW + c0);
    float4*        op = (float4*)(out + (size_t)n * HH * WW
                                      + (size_t)(h0 + row) * WW + c0);

    float4 xin[8];
    #pragma unroll
    for (int i = 0; i < 8; ++i) xin[i] = xp[i];   // early: hides under LDS work

    // T = sum of LDS cols [c0, c0+67]  (17 4-col chunks)
    float4 t4 = make_float4(0, 0, 0, 0), u4 = make_float4(0, 0, 0, 0);
    #pragma unroll
    for (int i = 0; i < 16; i += 2) {
        float4 a = ld4(crow, c0 + 4 * i);
        float4 b = ld4(crow, c0 + 4 * (i + 1));
        t4.x += a.x; t4.y += a.y; t4.z += a.z; t4.w += a.w;
        u4.x += b.x; u4.y += b.y; u4.z += b.z; u4.w += b.w;
    }
    float T = hsum4(t4) + hsum4(u4) + hsum4(ld4(crow, c0 + 64));

    #pragma unroll
    for (int g = 0; g < 8; ++g) {
        float4 vin  = ld4(crow, c0 + 68 + 4 * g);  // entering cols
        float4 vout = ld4(crow, c0 + 4 * g);       // leaving cols
        float pin0 = vin.x,  pin1 = pin0 + vin.y,
              pin2 = pin1 + vin.z, pin3 = pin2 + vin.w;
        float po0  = vout.x, po1 = po0 + vout.y,
              po2  = po1 + vout.z, po3 = po2 + vout.w;

        float4 xi = xin[g];
        float4 o;
        o.x = (xi.x - (T + pin0)       * INV) * 0.2f;
        o.y = (xi.y - (T + pin1 - po0) * INV) * 0.2f;
        o.z = (xi.z - (T + pin2 - po1) * INV) * 0.2f;
        o.w = (xi.w - (T + pin3 - po2) * INV) * 0.2f;
        op[g] = o;

        T += pin3 - po3;                // slide window by 4
    }
}

extern "C" void kernel_launch(void* const* d_in, const int* in_sizes, int n_in,
                              void* d_out, int out_size, void* d_ws, size_t ws_size,
                              hipStream_t stream) {
    const float* x   = (const float*)d_in[0];
    float*       out = (float*)d_out;

    int nblocks = NIMG * (HH / TH);     // 256 = 1 block/CU
    fused_kernel<<<nblocks, NT, 0, stream>>>(x, out);
}